// Round 5
// baseline (165.617 us; speedup 1.0000x reference)
//
#include <hip/hip_runtime.h>
#include <cstdint>

#define NPIX (512 * 512)

#if __has_builtin(__builtin_amdgcn_sbfe)
#define SEL1(m, k) __builtin_amdgcn_sbfe((m), (k), 1)   // v_bfe_i32: 0 or -1 in one op
#else
#define SEL1(m, k) (-(((m) >> (k)) & 1))
#endif

// ---------------- K1: argmax over 16 channels + passthrough copy + vec zero ----------------
__global__ __launch_bounds__(256) void k_argmax_copy(
    const float* __restrict__ enc, float* __restrict__ outc, uint8_t* __restrict__ labels,
    float* __restrict__ vecz) {
  if (blockIdx.x == 0) {                         // zero vec (ws is 0xAA-poisoned);
    for (int i = threadIdx.x; i < 16 * 480; i += 256) vecz[i] = 0.f;  // next dispatch consumes
  }
  int p = blockIdx.x * 256 + threadIdx.x;        // 262144 threads, one pixel each
  float best = enc[p];
  outc[p] = best;
  int bi = 0;
  #pragma unroll
  for (int c = 1; c < 16; ++c) {
    float v = enc[c * NPIX + p];
    outc[c * NPIX + p] = v;
    if (v > best) { best = v; bi = c; }          // strict > keeps first index (argmax tie rule)
  }
  labels[p] = (uint8_t)bi;
}

// ---------------- K2: fused masks-pyramid (blocks 0..15) + level0 (blocks 16..1039) ----------------
__global__ __launch_bounds__(256) void k_masks_level0(
    const uint8_t* __restrict__ labels, const float* __restrict__ f0,
    uint16_t* __restrict__ m1, uint16_t* __restrict__ m2, uint16_t* __restrict__ m3,
    unsigned* __restrict__ vec_u) {
  __shared__ unsigned s[16 * 33];
  if (blockIdx.x < 16) {
    // ---- masks path: pooled label-bitmask pyramids ----
    int t = blockIdx.x * 256 + threadIdx.x;      // 0..4095, one m3 pixel = 8x8 label block
    int y3 = t >> 6, x3 = t & 63;
    uint64_t rows[8];
    #pragma unroll
    for (int r = 0; r < 8; ++r)
      rows[r] = *(const uint64_t*)(labels + (size_t)(y3 * 8 + r) * 512 + x3 * 8);
    uint16_t m1v[4][4];
    uint16_t m2v[2][2] = {{0, 0}, {0, 0}};
    #pragma unroll
    for (int i = 0; i < 4; ++i) {
      uint64_t ra = rows[2 * i], rb = rows[2 * i + 1];
      #pragma unroll
      for (int j = 0; j < 4; ++j) {
        unsigned sh = 16u * j;
        uint16_t m = (uint16_t)((1u << ((ra >> sh) & 0xFF)) | (1u << ((ra >> (sh + 8)) & 0xFF)) |
                                (1u << ((rb >> sh) & 0xFF)) | (1u << ((rb >> (sh + 8)) & 0xFF)));
        m1v[i][j] = m;
        m2v[i >> 1][j >> 1] |= m;
      }
    }
    uint16_t m3v = (uint16_t)(m2v[0][0] | m2v[0][1] | m2v[1][0] | m2v[1][1]);
    #pragma unroll
    for (int i = 0; i < 4; ++i) {
      uint64_t pack = (uint64_t)m1v[i][0] | ((uint64_t)m1v[i][1] << 16) |
                      ((uint64_t)m1v[i][2] << 32) | ((uint64_t)m1v[i][3] << 48);
      *(uint64_t*)(m1 + (size_t)(y3 * 4 + i) * 256 + x3 * 4) = pack;
    }
    #pragma unroll
    for (int i = 0; i < 2; ++i) {
      uint32_t pack = (uint32_t)m2v[i][0] | ((uint32_t)m2v[i][1] << 16);
      *(uint32_t*)(m2 + (size_t)(y3 * 2 + i) * 128 + x3 * 2) = pack;
    }
    m3[y3 * 64 + x3] = m3v;
  } else {
    // ---- level0 path: f0 (32ch x 512²), LDS atomic max, 8 channels/block ----
    // stride 33: bank = (label+c)%32 spreads lanes with different labels.
    int bb = blockIdx.x - 16;
    for (int i = threadIdx.x; i < 16 * 33; i += 256) s[i] = 0u;
    __syncthreads();
    int cg = bb & 3;                             // channel group (8 channels)
    int g = (bb >> 2) * 256 + threadIdx.x;       // float4 pixel group, 65536 total
    uchar4 lb = *(const uchar4*)(labels + g * 4);
    const float4* f4 = (const float4*)f0;
    const int s4 = NPIX / 4;
    #pragma unroll
    for (int cc = 0; cc < 8; ++cc) {
      int c = cg * 8 + cc;
      float4 v = f4[c * s4 + g];
      atomicMax(&s[lb.x * 33 + c], __float_as_uint(fmaxf(v.x, 0.f)));
      atomicMax(&s[lb.y * 33 + c], __float_as_uint(fmaxf(v.y, 0.f)));
      atomicMax(&s[lb.z * 33 + c], __float_as_uint(fmaxf(v.z, 0.f)));
      atomicMax(&s[lb.w * 33 + c], __float_as_uint(fmaxf(v.w, 0.f)));
    }
    __syncthreads();
    if (threadIdx.x < 128) {
      int k = threadIdx.x >> 3, c = cg * 8 + (threadIdx.x & 7);
      atomicMax(&vec_u[k * 480 + c], s[k * 33 + c]);
    }
  }
}

// ---------------- K3: unified bitmask levels f1/f2/f3, uniform 8 iters/block ----------------
// 896 blocks: f1 [0,512): 16 cgroups x 32 chunks; f2 [512,768): 32 x 8; f3 [768,896): 64 x 2.
// chunkSize = 2048 everywhere -> nIter = 8 (4 px/lane/iter). Tail: LDS transpose reduce.
__global__ __launch_bounds__(256) void k_levels(
    const float* __restrict__ f1, const float* __restrict__ f2, const float* __restrict__ f3,
    const uint16_t* __restrict__ m1, const uint16_t* __restrict__ m2, const uint16_t* __restrict__ m3,
    unsigned* __restrict__ vec_u) {
  __shared__ unsigned sAcc[4][16][65];
  int b = blockIdx.x;
  const float* f; const uint16_t* masks; int P, lnChunks, vecBase;
  if (b < 512)      { f = f1; masks = m1; P = 65536; lnChunks = 5; vecBase = 32; }
  else if (b < 768) { b -= 512; f = f2; masks = m2; P = 16384; lnChunks = 3; vecBase = 96; }
  else              { b -= 768; f = f3; masks = m3; P = 4096;  lnChunks = 1; vecBase = 224; }
  int wave = threadIdx.x >> 6, lane = threadIdx.x & 63;
  int nChunks = 1 << lnChunks;
  int chunk = b & (nChunks - 1);
  int cg = b >> lnChunks;
  int c = cg * 4 + wave;
  int base = chunk * 2048;                       // chunkSize = 2048 uniformly
  const float* fp = f + (size_t)c * P + base + lane * 4;
  const uint16_t* mp = masks + base + lane * 4;
  int acc[16];
  #pragma unroll
  for (int k = 0; k < 16; ++k) acc[k] = 0;
  for (int it = 0; it < 8; ++it, fp += 256, mp += 256) {
    float4 v = *(const float4*)fp;
    uint64_t mm = *(const uint64_t*)mp;
    int vb0 = __float_as_int(fmaxf(v.x, 0.f)), vb1 = __float_as_int(fmaxf(v.y, 0.f));
    int vb2 = __float_as_int(fmaxf(v.z, 0.f)), vb3 = __float_as_int(fmaxf(v.w, 0.f));
    int m0 = (int)(mm & 0xFFFF), m1x = (int)((mm >> 16) & 0xFFFF);
    int m2x = (int)((mm >> 32) & 0xFFFF), m3x = (int)(mm >> 48);
    #pragma unroll
    for (int k = 0; k < 16; ++k) {
      int a01 = max(vb0 & SEL1(m0, k), vb1 & SEL1(m1x, k));
      int a23 = max(vb2 & SEL1(m2x, k), vb3 & SEL1(m3x, k));
      acc[k] = max(acc[k], max(a01, a23));       // vb >= 0 => int max == float max
    }
  }
  // phase 1: dump accs to LDS, banks (k+lane)%32 -> 2-way, free
  #pragma unroll
  for (int k = 0; k < 16; ++k) sAcc[wave][k][lane] = (unsigned)acc[k];
  __syncthreads();
  // phase 2: 256 threads; thread -> (w, k, part): reduce 16 lanes, then 4 parts via shfl
  int w = threadIdx.x >> 6, l = threadIdx.x & 63;
  int k = l >> 2, part = l & 3;
  const unsigned* row = &sAcc[w][k][part * 16];
  unsigned r = row[0];
  #pragma unroll
  for (int j = 1; j < 16; ++j) r = max(r, row[j]);
  r = max(r, (unsigned)__shfl_xor((int)r, 1, 64));
  r = max(r, (unsigned)__shfl_xor((int)r, 2, 64));
  if (part == 0)
    atomicMax(&vec_u[k * 480 + vecBase + cg * 4 + w], r);
}

// ---------------- K4: hid = vec(16x480) @ W1(480x240) + b1, LDS-tiled ----------------
__global__ __launch_bounds__(256) void k_mlp1(const float* __restrict__ vecf,
    const float* __restrict__ W1, const float* __restrict__ b1, float* __restrict__ hid) {
  __shared__ float v[16 * 484];
  __shared__ float w[480 * 8];
  int t = threadIdx.x;
  int colBase = blockIdx.x * 8;
  for (int i = t; i < 16 * 480; i += 256) {
    int r = i / 480, j = i - r * 480;
    v[r * 484 + j] = vecf[i];
  }
  for (int i = t; i < 480 * 8; i += 256) {
    int j = i >> 3, col = i & 7;
    w[i] = W1[j * 240 + colBase + col];
  }
  __syncthreads();
  if (t < 128) {
    int r = t >> 3, col = t & 7;
    const float* vr = v + r * 484;
    float a0 = 0.f, a1 = 0.f, a2 = 0.f, a3 = 0.f;
    for (int j = 0; j < 480; j += 4) {
      a0 += vr[j]     * w[j * 8 + col];
      a1 += vr[j + 1] * w[(j + 1) * 8 + col];
      a2 += vr[j + 2] * w[(j + 2) * 8 + col];
      a3 += vr[j + 3] * w[(j + 3) * 8 + col];
    }
    hid[r * 240 + colBase + col] = a0 + a1 + a2 + a3 + b1[colBase + col];
  }
}

// ---------------- K5: bbox = sigmoid(hid(16x240) @ W2(240x4) + b2), rows 1..15 ----------------
__global__ __launch_bounds__(256) void k_mlp2(const float* __restrict__ hid,
    const float* __restrict__ W2, const float* __restrict__ b2, float* __restrict__ out) {
  __shared__ float h[16 * 241];
  __shared__ float w[240 * 4];
  int t = threadIdx.x;
  for (int i = t; i < 16 * 240; i += 256) {
    int r = i / 240, j = i - r * 240;
    h[r * 241 + j] = hid[i];
  }
  for (int i = t; i < 960; i += 256) w[i] = W2[i];
  __syncthreads();
  if (t < 64) {
    int k = t >> 2, o = t & 3;
    const float* hk = h + k * 241;
    float a0 = b2[o], a1 = 0.f;
    for (int j = 0; j < 240; j += 2) {
      a0 += hk[j]     * w[j * 4 + o];
      a1 += hk[j + 1] * w[(j + 1) * 4 + o];
    }
    float a = a0 + a1;
    float s = 1.f / (1.f + __expf(-a));
    if (k >= 1) out[(k - 1) * 4 + o] = s;   // rows 1..15 only
  }
}

extern "C" void kernel_launch(void* const* d_in, const int* in_sizes, int n_in,
                              void* d_out, int out_size, void* d_ws, size_t ws_size,
                              hipStream_t stream) {
  const float* enc = (const float*)d_in[0];
  const float* f0  = (const float*)d_in[1];
  const float* f1  = (const float*)d_in[2];
  const float* f2  = (const float*)d_in[3];
  const float* f3  = (const float*)d_in[4];
  const float* W1  = (const float*)d_in[5];
  const float* b1  = (const float*)d_in[6];
  const float* W2  = (const float*)d_in[7];
  const float* b2  = (const float*)d_in[8];
  float* out = (float*)d_out;                 // [0:60) bboxes, [60:) encoded copy
  char* ws = (char*)d_ws;

  uint8_t*  labels = (uint8_t*)ws;                     // 262144 B
  uint16_t* m1     = (uint16_t*)(ws + 262144);         // 131072 B
  uint16_t* m2     = (uint16_t*)(ws + 393216);         //  32768 B
  uint16_t* m3     = (uint16_t*)(ws + 425984);         //   8192 B
  float*    vec    = (float*)(ws + 434176);            //  30720 B (16 x 480)
  float*    hid    = (float*)(ws + 464896);            //  15360 B (16 x 240)
  unsigned* vec_u  = (unsigned*)vec;

  k_argmax_copy<<<1024, 256, 0, stream>>>(enc, out + 60, labels, vec);
  k_masks_level0<<<1040, 256, 0, stream>>>(labels, f0, m1, m2, m3, vec_u);
  k_levels<<<896, 256, 0, stream>>>(f1, f2, f3, m1, m2, m3, vec_u);
  k_mlp1<<<30, 256, 0, stream>>>(vec, W1, b1, hid);
  k_mlp2<<<1, 256, 0, stream>>>(hid, W2, b2, out);
}

// Round 6
// 163.873 us; speedup vs baseline: 1.0106x; 1.0106x over previous
//
#include <hip/hip_runtime.h>
#include <cstdint>

#define NPIX (512 * 512)

#if __has_builtin(__builtin_amdgcn_sbfe)
#define SEL1(m, k) __builtin_amdgcn_sbfe((m), (k), 1)   // v_bfe_i32: 0 or -1 in one op
#else
#define SEL1(m, k) (-(((m) >> (k)) & 1))
#endif

// ---------------- K1: argmax over 16 channels + passthrough copy (per-pixel) ----------------
__global__ __launch_bounds__(256) void k_argmax_copy(
    const float* __restrict__ enc, float* __restrict__ outc, uint8_t* __restrict__ labels) {
  int p = blockIdx.x * 256 + threadIdx.x;        // 262144 threads, one pixel each
  float best = enc[p];
  outc[p] = best;
  int bi = 0;
  #pragma unroll
  for (int c = 1; c < 16; ++c) {
    float v = enc[c * NPIX + p];
    outc[c * NPIX + p] = v;
    if (v > best) { best = v; bi = c; }          // strict > keeps first index (argmax tie rule)
  }
  labels[p] = (uint8_t)bi;
}

// ---------------- K2: pooled label-bitmask pyramids + zero vec ----------------
__global__ __launch_bounds__(256) void k_masks(const uint8_t* __restrict__ labels,
    uint16_t* __restrict__ m1, uint16_t* __restrict__ m2, uint16_t* __restrict__ m3,
    float* __restrict__ vecz) {
  int t = blockIdx.x * 256 + threadIdx.x;        // 0..4095, one m3 pixel = 8x8 label block
  for (int i = t; i < 16 * 480; i += 4096) vecz[i] = 0.f;   // zero vec (ws is 0xAA-poisoned)
  int y3 = t >> 6, x3 = t & 63;
  uint64_t rows[8];
  #pragma unroll
  for (int r = 0; r < 8; ++r)
    rows[r] = *(const uint64_t*)(labels + (size_t)(y3 * 8 + r) * 512 + x3 * 8);
  uint16_t m1v[4][4];
  uint16_t m2v[2][2] = {{0, 0}, {0, 0}};
  #pragma unroll
  for (int i = 0; i < 4; ++i) {
    uint64_t ra = rows[2 * i], rb = rows[2 * i + 1];
    #pragma unroll
    for (int j = 0; j < 4; ++j) {
      unsigned sh = 16u * j;
      uint16_t m = (uint16_t)((1u << ((ra >> sh) & 0xFF)) | (1u << ((ra >> (sh + 8)) & 0xFF)) |
                              (1u << ((rb >> sh) & 0xFF)) | (1u << ((rb >> (sh + 8)) & 0xFF)));
      m1v[i][j] = m;
      m2v[i >> 1][j >> 1] |= m;
    }
  }
  uint16_t m3v = (uint16_t)(m2v[0][0] | m2v[0][1] | m2v[1][0] | m2v[1][1]);
  #pragma unroll
  for (int i = 0; i < 4; ++i) {
    uint64_t pack = (uint64_t)m1v[i][0] | ((uint64_t)m1v[i][1] << 16) |
                    ((uint64_t)m1v[i][2] << 32) | ((uint64_t)m1v[i][3] << 48);
    *(uint64_t*)(m1 + (size_t)(y3 * 4 + i) * 256 + x3 * 4) = pack;
  }
  #pragma unroll
  for (int i = 0; i < 2; ++i) {
    uint32_t pack = (uint32_t)m2v[i][0] | ((uint32_t)m2v[i][1] << 16);
    *(uint32_t*)(m2 + (size_t)(y3 * 2 + i) * 128 + x3 * 2) = pack;
  }
  m3[y3 * 64 + x3] = m3v;
}

// ---------------- K3: level 0 (f0: 32ch x 512²), LDS atomic max, 8 channels/block ----------------
// stride 33: bank = (label+c)%32, spreads lanes with different labels.
__global__ __launch_bounds__(256) void k_level0(const float* __restrict__ f0,
    const uint8_t* __restrict__ labels, unsigned* __restrict__ vec_u) {
  __shared__ unsigned s[16 * 33];
  for (int i = threadIdx.x; i < 16 * 33; i += 256) s[i] = 0u;
  __syncthreads();
  int cg = blockIdx.x & 3;                       // channel group (8 channels)
  int g = (blockIdx.x >> 2) * 256 + threadIdx.x; // float4 pixel group, 65536 total
  uchar4 lb = *(const uchar4*)(labels + g * 4);
  const float4* f4 = (const float4*)f0;
  const int s4 = NPIX / 4;
  #pragma unroll
  for (int cc = 0; cc < 8; ++cc) {
    int c = cg * 8 + cc;
    float4 v = f4[c * s4 + g];
    atomicMax(&s[lb.x * 33 + c], __float_as_uint(fmaxf(v.x, 0.f)));
    atomicMax(&s[lb.y * 33 + c], __float_as_uint(fmaxf(v.y, 0.f)));
    atomicMax(&s[lb.z * 33 + c], __float_as_uint(fmaxf(v.z, 0.f)));
    atomicMax(&s[lb.w * 33 + c], __float_as_uint(fmaxf(v.w, 0.f)));
  }
  __syncthreads();
  if (threadIdx.x < 128) {
    int k = threadIdx.x >> 3, c = cg * 8 + (threadIdx.x & 7);
    atomicMax(&vec_u[k * 480 + c], s[k * 33 + c]);
  }
}

// ---------------- K4: unified bitmask levels f1/f2/f3 (R4-validated grid) ----------------
// 768 blocks (3/CU, all resident). f1 [0,256): 16 cgroups x 16 chunks, nIter=16.
// f2 [256,512): 32 x 8, nIter=8. f3 [512,768): 64 x 4, nIter=4.
// Tail: LDS transpose reduce (stride 65 -> conflict-free) instead of 96-op shfl tree.
__global__ __launch_bounds__(256) void k_levels(
    const float* __restrict__ f1, const float* __restrict__ f2, const float* __restrict__ f3,
    const uint16_t* __restrict__ m1, const uint16_t* __restrict__ m2, const uint16_t* __restrict__ m3,
    unsigned* __restrict__ vec_u) {
  __shared__ unsigned sAcc[4][16][65];
  int b = blockIdx.x;
  const float* f; const uint16_t* masks; int P, lnChunks, vecBase;
  if (b < 256)      { f = f1; masks = m1; P = 65536; lnChunks = 4; vecBase = 32; }
  else if (b < 512) { b -= 256; f = f2; masks = m2; P = 16384; lnChunks = 3; vecBase = 96; }
  else              { b -= 512; f = f3; masks = m3; P = 4096;  lnChunks = 2; vecBase = 224; }
  int wave = threadIdx.x >> 6, lane = threadIdx.x & 63;
  int nChunks = 1 << lnChunks;
  int chunk = b & (nChunks - 1);
  int cg = b >> lnChunks;
  int c = cg * 4 + wave;
  int chunkSize = P >> lnChunks;                 // 4096 / 2048 / 1024
  int base = chunk * chunkSize;
  const float* fp = f + (size_t)c * P + base + lane * 4;
  const uint16_t* mp = masks + base + lane * 4;
  int acc[16];
  #pragma unroll
  for (int k = 0; k < 16; ++k) acc[k] = 0;
  int nIter = chunkSize >> 8;                    // 16 / 8 / 4 (4 px/lane/iter)
  for (int it = 0; it < nIter; ++it, fp += 256, mp += 256) {
    float4 v = *(const float4*)fp;
    uint64_t mm = *(const uint64_t*)mp;
    int vb0 = __float_as_int(fmaxf(v.x, 0.f)), vb1 = __float_as_int(fmaxf(v.y, 0.f));
    int vb2 = __float_as_int(fmaxf(v.z, 0.f)), vb3 = __float_as_int(fmaxf(v.w, 0.f));
    int m0 = (int)(mm & 0xFFFF), m1x = (int)((mm >> 16) & 0xFFFF);
    int m2x = (int)((mm >> 32) & 0xFFFF), m3x = (int)(mm >> 48);
    #pragma unroll
    for (int k = 0; k < 16; ++k) {
      int a01 = max(vb0 & SEL1(m0, k), vb1 & SEL1(m1x, k));
      int a23 = max(vb2 & SEL1(m2x, k), vb3 & SEL1(m3x, k));
      acc[k] = max(acc[k], max(a01, a23));       // vb >= 0 => int max == float max
    }
  }
  // phase 1: dump accs to LDS, banks (k+lane)%32 -> 2-way, free
  #pragma unroll
  for (int k = 0; k < 16; ++k) sAcc[wave][k][lane] = (unsigned)acc[k];
  __syncthreads();
  // phase 2: 256 threads; thread -> (w, k, part): reduce 16 lanes, then 4 parts via shfl
  int w = threadIdx.x >> 6, l = threadIdx.x & 63;
  int k = l >> 2, part = l & 3;
  const unsigned* row = &sAcc[w][k][part * 16];
  unsigned r = row[0];
  #pragma unroll
  for (int j = 1; j < 16; ++j) r = max(r, row[j]);
  r = max(r, (unsigned)__shfl_xor((int)r, 1, 64));
  r = max(r, (unsigned)__shfl_xor((int)r, 2, 64));
  if (part == 0)
    atomicMax(&vec_u[k * 480 + vecBase + cg * 4 + w], r);
}

// ---------------- K5: fused MLP. One block per label row k. ----------------
// Phase 1: 480 threads (two 240-row halves) compute partial hid; coalesced W1 reads.
// Phase 2: combine halves + b1. Phase 3: 64 threads, 240x4 layer + shfl reduce + sigmoid.
__global__ __launch_bounds__(512) void k_mlp(const float* __restrict__ vecf,
    const float* __restrict__ W1, const float* __restrict__ b1,
    const float* __restrict__ W2, const float* __restrict__ b2, float* __restrict__ out) {
  __shared__ float v[480];
  __shared__ float part[480];
  __shared__ float hid[240];
  __shared__ float w2s[240 * 4];
  int k = blockIdx.x, t = threadIdx.x;
  if (t < 480) v[t] = vecf[k * 480 + t];
  for (int i = t; i < 960; i += 512) w2s[i] = W2[i];
  __syncthreads();
  if (t < 480) {
    int col = (t >= 240) ? t - 240 : t;          // hid column
    int i0 = (t >= 240) ? 240 : 0;               // which half of the 480 rows
    float a0 = 0.f, a1 = 0.f, a2 = 0.f, a3 = 0.f;
    #pragma unroll 2
    for (int i = 0; i < 240; i += 4) {
      a0 += v[i0 + i]     * W1[(i0 + i) * 240 + col];
      a1 += v[i0 + i + 1] * W1[(i0 + i + 1) * 240 + col];
      a2 += v[i0 + i + 2] * W1[(i0 + i + 2) * 240 + col];
      a3 += v[i0 + i + 3] * W1[(i0 + i + 3) * 240 + col];
    }
    part[t] = a0 + a1 + a2 + a3;
  }
  __syncthreads();
  if (t < 240) hid[t] = part[t] + part[t + 240] + b1[t];
  __syncthreads();
  if (t < 64) {                                  // one wave: o = t&3, part p = t>>2 (16x15 rows)
    int o = t & 3, p = t >> 2;
    float s = 0.f;
    #pragma unroll
    for (int j = p * 15; j < p * 15 + 15; ++j) s += hid[j] * w2s[j * 4 + o];
    #pragma unroll
    for (int off = 4; off < 64; off <<= 1)       // sum over p (offsets multiple of 4 keep o)
      s += __shfl_xor(s, off, 64);
    if (p == 0) {
      float a = s + b2[o];
      float sg = 1.f / (1.f + __expf(-a));
      if (k >= 1) out[(k - 1) * 4 + o] = sg;     // rows 1..15 only
    }
  }
}

extern "C" void kernel_launch(void* const* d_in, const int* in_sizes, int n_in,
                              void* d_out, int out_size, void* d_ws, size_t ws_size,
                              hipStream_t stream) {
  const float* enc = (const float*)d_in[0];
  const float* f0  = (const float*)d_in[1];
  const float* f1  = (const float*)d_in[2];
  const float* f2  = (const float*)d_in[3];
  const float* f3  = (const float*)d_in[4];
  const float* W1  = (const float*)d_in[5];
  const float* b1  = (const float*)d_in[6];
  const float* W2  = (const float*)d_in[7];
  const float* b2  = (const float*)d_in[8];
  float* out = (float*)d_out;                 // [0:60) bboxes, [60:) encoded copy
  char* ws = (char*)d_ws;

  uint8_t*  labels = (uint8_t*)ws;                     // 262144 B
  uint16_t* m1     = (uint16_t*)(ws + 262144);         // 131072 B
  uint16_t* m2     = (uint16_t*)(ws + 393216);         //  32768 B
  uint16_t* m3     = (uint16_t*)(ws + 425984);         //   8192 B
  float*    vec    = (float*)(ws + 434176);            //  30720 B (16 x 480)
  unsigned* vec_u  = (unsigned*)vec;

  k_argmax_copy<<<1024, 256, 0, stream>>>(enc, out + 60, labels);
  k_masks<<<16, 256, 0, stream>>>(labels, m1, m2, m3, vec);
  k_level0<<<1024, 256, 0, stream>>>(f0, labels, vec_u);
  k_levels<<<768, 256, 0, stream>>>(f1, f2, f3, m1, m2, m3, vec_u);
  k_mlp<<<16, 512, 0, stream>>>(vec, W1, b1, W2, b2, out);
}

// Round 8
// 158.495 us; speedup vs baseline: 1.0449x; 1.0339x over previous
//
#include <hip/hip_runtime.h>
#include <cstdint>

#define NPIX (512 * 512)

typedef float f32x4 __attribute__((ext_vector_type(4)));  // native vec: OK for nontemporal builtin

#if __has_builtin(__builtin_amdgcn_sbfe)
#define SEL1(m, k) __builtin_amdgcn_sbfe((m), (k), 1)   // v_bfe_i32: 0 or -1 in one op
#else
#define SEL1(m, k) (-(((m) >> (k)) & 1))
#endif

// ---------------- K1: argmax over 16 channels + passthrough copy (per-pixel) ----------------
__global__ __launch_bounds__(256) void k_argmax_copy(
    const float* __restrict__ enc, float* __restrict__ outc, uint8_t* __restrict__ labels) {
  int p = blockIdx.x * 256 + threadIdx.x;        // 262144 threads, one pixel each
  float best = enc[p];
  outc[p] = best;
  int bi = 0;
  #pragma unroll
  for (int c = 1; c < 16; ++c) {
    float v = enc[c * NPIX + p];
    outc[c * NPIX + p] = v;
    if (v > best) { best = v; bi = c; }          // strict > keeps first index (argmax tie rule)
  }
  labels[p] = (uint8_t)bi;
}

// ---------------- K2: pooled label-bitmask pyramids + zero vec ----------------
__global__ __launch_bounds__(256) void k_masks(const uint8_t* __restrict__ labels,
    uint16_t* __restrict__ m1, uint16_t* __restrict__ m2, uint16_t* __restrict__ m3,
    float* __restrict__ vecz) {
  int t = blockIdx.x * 256 + threadIdx.x;        // 0..4095, one m3 pixel = 8x8 label block
  for (int i = t; i < 16 * 480; i += 4096) vecz[i] = 0.f;   // zero vec (ws is 0xAA-poisoned)
  int y3 = t >> 6, x3 = t & 63;
  uint64_t rows[8];
  #pragma unroll
  for (int r = 0; r < 8; ++r)
    rows[r] = *(const uint64_t*)(labels + (size_t)(y3 * 8 + r) * 512 + x3 * 8);
  uint16_t m1v[4][4];
  uint16_t m2v[2][2] = {{0, 0}, {0, 0}};
  #pragma unroll
  for (int i = 0; i < 4; ++i) {
    uint64_t ra = rows[2 * i], rb = rows[2 * i + 1];
    #pragma unroll
    for (int j = 0; j < 4; ++j) {
      unsigned sh = 16u * j;
      uint16_t m = (uint16_t)((1u << ((ra >> sh) & 0xFF)) | (1u << ((ra >> (sh + 8)) & 0xFF)) |
                              (1u << ((rb >> sh) & 0xFF)) | (1u << ((rb >> (sh + 8)) & 0xFF)));
      m1v[i][j] = m;
      m2v[i >> 1][j >> 1] |= m;
    }
  }
  uint16_t m3v = (uint16_t)(m2v[0][0] | m2v[0][1] | m2v[1][0] | m2v[1][1]);
  #pragma unroll
  for (int i = 0; i < 4; ++i) {
    uint64_t pack = (uint64_t)m1v[i][0] | ((uint64_t)m1v[i][1] << 16) |
                    ((uint64_t)m1v[i][2] << 32) | ((uint64_t)m1v[i][3] << 48);
    *(uint64_t*)(m1 + (size_t)(y3 * 4 + i) * 256 + x3 * 4) = pack;
  }
  #pragma unroll
  for (int i = 0; i < 2; ++i) {
    uint32_t pack = (uint32_t)m2v[i][0] | ((uint32_t)m2v[i][1] << 16);
    *(uint32_t*)(m2 + (size_t)(y3 * 2 + i) * 128 + x3 * 2) = pack;
  }
  m3[y3 * 64 + x3] = m3v;
}

// ---------------- K3: level 0 (f0: 32ch x 512²), LDS atomic max, 8 channels/block ----------------
// stride 33: bank = (label+c)%32, spreads lanes with different labels.
__global__ __launch_bounds__(256) void k_level0(const float* __restrict__ f0,
    const uint8_t* __restrict__ labels, unsigned* __restrict__ vec_u) {
  __shared__ unsigned s[16 * 33];
  for (int i = threadIdx.x; i < 16 * 33; i += 256) s[i] = 0u;
  __syncthreads();
  int cg = blockIdx.x & 3;                       // channel group (8 channels)
  int g = (blockIdx.x >> 2) * 256 + threadIdx.x; // float4 pixel group, 65536 total
  uchar4 lb = *(const uchar4*)(labels + g * 4);
  const float4* f4 = (const float4*)f0;
  const int s4 = NPIX / 4;
  #pragma unroll
  for (int cc = 0; cc < 8; ++cc) {
    int c = cg * 8 + cc;
    float4 v = f4[c * s4 + g];
    atomicMax(&s[lb.x * 33 + c], __float_as_uint(fmaxf(v.x, 0.f)));
    atomicMax(&s[lb.y * 33 + c], __float_as_uint(fmaxf(v.y, 0.f)));
    atomicMax(&s[lb.z * 33 + c], __float_as_uint(fmaxf(v.z, 0.f)));
    atomicMax(&s[lb.w * 33 + c], __float_as_uint(fmaxf(v.w, 0.f)));
  }
  __syncthreads();
  if (threadIdx.x < 128) {
    int k = threadIdx.x >> 3, c = cg * 8 + (threadIdx.x & 7);
    atomicMax(&vec_u[k * 480 + c], s[k * 33 + c]);
  }
}

// ---------------- K4: unified bitmask levels f1/f2/f3 (R4 grid + 2-deep prefetch) ----------------
// 768 blocks (3/CU). f1 [0,256): 16 cgroups x 16 chunks, nIter=16. f2 [256,512): 32 x 8, nIter=8.
// f3 [512,768): 64 x 4, nIter=4. Next-iter loads issued BEFORE processing current iter
// (2x loads in flight per wave); feature stream nontemporal (single-use), masks cached (16x reuse).
__global__ __launch_bounds__(256) void k_levels(
    const float* __restrict__ f1, const float* __restrict__ f2, const float* __restrict__ f3,
    const uint16_t* __restrict__ m1, const uint16_t* __restrict__ m2, const uint16_t* __restrict__ m3,
    unsigned* __restrict__ vec_u) {
  __shared__ unsigned sAcc[4][16][65];
  int b = blockIdx.x;
  const float* f; const uint16_t* masks; int P, lnChunks, vecBase;
  if (b < 256)      { f = f1; masks = m1; P = 65536; lnChunks = 4; vecBase = 32; }
  else if (b < 512) { b -= 256; f = f2; masks = m2; P = 16384; lnChunks = 3; vecBase = 96; }
  else              { b -= 512; f = f3; masks = m3; P = 4096;  lnChunks = 2; vecBase = 224; }
  int wave = threadIdx.x >> 6, lane = threadIdx.x & 63;
  int nChunks = 1 << lnChunks;
  int chunk = b & (nChunks - 1);
  int cg = b >> lnChunks;
  int c = cg * 4 + wave;
  int chunkSize = P >> lnChunks;                 // 4096 / 2048 / 1024
  int base = chunk * chunkSize;
  const f32x4* fp4 = (const f32x4*)(f + (size_t)c * P + base) + lane;
  const uint64_t* mp8 = (const uint64_t*)(masks + base) + lane;
  int acc[16];
  #pragma unroll
  for (int k = 0; k < 16; ++k) acc[k] = 0;
  int nIter = chunkSize >> 8;                    // 16 / 8 / 4 (4 px/lane/iter)
  f32x4 v = __builtin_nontemporal_load(fp4);
  uint64_t mm = *mp8;
  for (int it = 0; it < nIter; ++it) {
    f32x4 vn = v; uint64_t mn = mm;
    if (it + 1 < nIter) {                        // wave-uniform branch; prefetch next iter
      vn = __builtin_nontemporal_load(fp4 + (it + 1) * 64);
      mn = mp8[(it + 1) * 32];
    }
    int vb0 = __float_as_int(fmaxf(v.x, 0.f)), vb1 = __float_as_int(fmaxf(v.y, 0.f));
    int vb2 = __float_as_int(fmaxf(v.z, 0.f)), vb3 = __float_as_int(fmaxf(v.w, 0.f));
    int m0 = (int)(mm & 0xFFFF), m1x = (int)((mm >> 16) & 0xFFFF);
    int m2x = (int)((mm >> 32) & 0xFFFF), m3x = (int)(mm >> 48);
    #pragma unroll
    for (int k = 0; k < 16; ++k) {
      int a01 = max(vb0 & SEL1(m0, k), vb1 & SEL1(m1x, k));
      int a23 = max(vb2 & SEL1(m2x, k), vb3 & SEL1(m3x, k));
      acc[k] = max(acc[k], max(a01, a23));       // vb >= 0 => int max == float max
    }
    v = vn; mm = mn;
  }
  // phase 1: dump accs to LDS, banks (k+lane)%32 -> 2-way, free
  #pragma unroll
  for (int k = 0; k < 16; ++k) sAcc[wave][k][lane] = (unsigned)acc[k];
  __syncthreads();
  // phase 2: 256 threads; thread -> (w, k, part): reduce 16 lanes, then 4 parts via shfl
  int w = threadIdx.x >> 6, l = threadIdx.x & 63;
  int k = l >> 2, part = l & 3;
  const unsigned* row = &sAcc[w][k][part * 16];
  unsigned r = row[0];
  #pragma unroll
  for (int j = 1; j < 16; ++j) r = max(r, row[j]);
  r = max(r, (unsigned)__shfl_xor((int)r, 1, 64));
  r = max(r, (unsigned)__shfl_xor((int)r, 2, 64));
  if (part == 0)
    atomicMax(&vec_u[k * 480 + vecBase + cg * 4 + w], r);
}

// ---------------- K5a: hid = vec(16x480) @ W1(480x240) + b1, LDS-tiled (R4-validated) ----------------
__global__ __launch_bounds__(256) void k_mlp1(const float* __restrict__ vecf,
    const float* __restrict__ W1, const float* __restrict__ b1, float* __restrict__ hid) {
  __shared__ float v[16 * 484];
  __shared__ float w[480 * 8];
  int t = threadIdx.x;
  int colBase = blockIdx.x * 8;
  for (int i = t; i < 16 * 480; i += 256) {
    int r = i / 480, j = i - r * 480;
    v[r * 484 + j] = vecf[i];
  }
  for (int i = t; i < 480 * 8; i += 256) {
    int j = i >> 3, col = i & 7;
    w[i] = W1[j * 240 + colBase + col];
  }
  __syncthreads();
  if (t < 128) {
    int r = t >> 3, col = t & 7;
    const float* vr = v + r * 484;
    float a0 = 0.f, a1 = 0.f, a2 = 0.f, a3 = 0.f;
    for (int j = 0; j < 480; j += 4) {
      a0 += vr[j]     * w[j * 8 + col];
      a1 += vr[j + 1] * w[(j + 1) * 8 + col];
      a2 += vr[j + 2] * w[(j + 2) * 8 + col];
      a3 += vr[j + 3] * w[(j + 3) * 8 + col];
    }
    hid[r * 240 + colBase + col] = a0 + a1 + a2 + a3 + b1[colBase + col];
  }
}

// ---------------- K5b: bbox = sigmoid(hid(16x240) @ W2(240x4) + b2), rows 1..15 ----------------
__global__ __launch_bounds__(256) void k_mlp2(const float* __restrict__ hid,
    const float* __restrict__ W2, const float* __restrict__ b2, float* __restrict__ out) {
  __shared__ float h[16 * 241];
  __shared__ float w[240 * 4];
  int t = threadIdx.x;
  for (int i = t; i < 16 * 240; i += 256) {
    int r = i / 240, j = i - r * 240;
    h[r * 241 + j] = hid[i];
  }
  for (int i = t; i < 960; i += 256) w[i] = W2[i];
  __syncthreads();
  if (t < 64) {
    int k = t >> 2, o = t & 3;
    const float* hk = h + k * 241;
    float a0 = b2[o], a1 = 0.f;
    for (int j = 0; j < 240; j += 2) {
      a0 += hk[j]     * w[j * 4 + o];
      a1 += hk[j + 1] * w[(j + 1) * 4 + o];
    }
    float a = a0 + a1;
    float s = 1.f / (1.f + __expf(-a));
    if (k >= 1) out[(k - 1) * 4 + o] = s;   // rows 1..15 only
  }
}

extern "C" void kernel_launch(void* const* d_in, const int* in_sizes, int n_in,
                              void* d_out, int out_size, void* d_ws, size_t ws_size,
                              hipStream_t stream) {
  const float* enc = (const float*)d_in[0];
  const float* f0  = (const float*)d_in[1];
  const float* f1  = (const float*)d_in[2];
  const float* f2  = (const float*)d_in[3];
  const float* f3  = (const float*)d_in[4];
  const float* W1  = (const float*)d_in[5];
  const float* b1  = (const float*)d_in[6];
  const float* W2  = (const float*)d_in[7];
  const float* b2  = (const float*)d_in[8];
  float* out = (float*)d_out;                 // [0:60) bboxes, [60:) encoded copy
  char* ws = (char*)d_ws;

  uint8_t*  labels = (uint8_t*)ws;                     // 262144 B
  uint16_t* m1     = (uint16_t*)(ws + 262144);         // 131072 B
  uint16_t* m2     = (uint16_t*)(ws + 393216);         //  32768 B
  uint16_t* m3     = (uint16_t*)(ws + 425984);         //   8192 B
  float*    vec    = (float*)(ws + 434176);            //  30720 B (16 x 480)
  float*    hid    = (float*)(ws + 464896);            //  15360 B (16 x 240)
  unsigned* vec_u  = (unsigned*)vec;

  k_argmax_copy<<<1024, 256, 0, stream>>>(enc, out + 60, labels);
  k_masks<<<16, 256, 0, stream>>>(labels, m1, m2, m3, vec);
  k_level0<<<1024, 256, 0, stream>>>(f0, labels, vec_u);
  k_levels<<<768, 256, 0, stream>>>(f1, f2, f3, m1, m2, m3, vec_u);
  k_mlp1<<<30, 256, 0, stream>>>(vec, W1, b1, hid);
  k_mlp2<<<1, 256, 0, stream>>>(hid, W2, b2, out);
}